// Round 6
// baseline (210.847 us; speedup 1.0000x reference)
//
#include <hip/hip_runtime.h>
#include <hip/hip_bf16.h>
#include <math.h>

// TinyMoE: out = sum_e softmax(x@Wr)[e] * (gelu(x@w1[e]+b1[e]) @ w2[e] + b2[e])
// v7: SPLIT into two streaming GEMM kernels through an H buffer in workspace.
//     v1-v6 post-mortem: fused kernel = serial sum of HBM(16us)+MFMA(9)+VALU(8)+LDS(6)
//     ~= 43-51us; lockstep blocks never overlap phases; deeper pipelining is
//     register-impossible. Split pays +37MB HBM (H round-trip, bf16 [32768][288])
//     but each kernel is barrier-free, LDS-free streaming at 3 blocks/CU
//     (12 waves/CU) -> phases overlap via wave-level parallelism.
//     K1: GEMM1 + router fold + in-reg softmax + fast-erf gelu*wt -> H bf16.
//     K2: GEMM2 (H @ W2'), A-fragments read directly from global, no LDS/barriers.

typedef short v8s __attribute__((ext_vector_type(8)));
typedef float v4f __attribute__((ext_vector_type(4)));

__device__ __forceinline__ unsigned short f2bf(float f) {
    unsigned int u = __builtin_bit_cast(unsigned int, f);
    u += 0x7fffu + ((u >> 16) & 1u);
    return (unsigned short)(u >> 16);
}
__device__ __forceinline__ unsigned int pk2(float lo, float hi) {
    return (unsigned int)f2bf(lo) | ((unsigned int)f2bf(hi) << 16);
}
// exact-gelu via Abramowitz-Stegun 7.1.26 erf (|err|<=1.5e-7, safe at bf16 tolerance)
__device__ __forceinline__ float gelu_fast(float v) {
    float s  = v * 0.70710678118f;
    float xa = fabsf(s);
    float t  = 1.0f / (1.0f + 0.3275911f * xa);
    float poly = t * (0.254829592f + t * (-0.284496736f + t * (1.421413741f +
                 t * (-1.453152027f + t * 1.061405429f))));
    float er = 1.0f - poly * __expf(-xa * xa);
    er = copysignf(er, s);
    return 0.5f * v * (1.0f + er);
}

// ---- prep: pack weights into bf16 MFMA B-fragment layout in workspace (unchanged) ----
// Block = 16(N) x 32(K) bf16, stored as [n_local*32 + k_local], 512 elems = 1KB.
// Lane l of a wave reads 16B at ((l&15)*32 + (l>>4)*8)*2 -> B[k][n], n=l&15, k=(l>>4)*8+j.
__global__ void moe_prep(const float* __restrict__ w1,   // (4,512,64)
                         const float* __restrict__ w2,   // (4,64,512)
                         const float* __restrict__ b2,   // (4,512)
                         const float* __restrict__ rw,   // (512,4)
                         unsigned short* __restrict__ w1p,
                         unsigned short* __restrict__ w2p,
                         unsigned short* __restrict__ rp) {
    int idx = blockIdx.x * 256 + threadIdx.x;
    if (idx < 131072) {
        // W1' [K=512][N=256], block = kb*16 + cb
        int block = idx >> 9, within = idx & 511;
        int kb = block >> 4, cb = block & 15;
        int n = within >> 5, kl = within & 31;
        int k = kb * 32 + kl;
        int col = cb * 16 + n;          // col in [0,256): e = col>>6, h = col&63
        int e = col >> 6, h = col & 63;
        w1p[idx] = f2bf(w1[(e * 512 + k) * 64 + h]);
    } else if (idx < 131072 + 147456) {
        // W2' [Kpad=288][N=512], block = kb*32 + cb. k in [256,260) = b2 rows, >=260 zero.
        int op = idx - 131072;
        int block = op >> 9, within = op & 511;
        int kb = block >> 5, cb = block & 31;
        int n = within >> 5, kl = within & 31;
        int k = kb * 32 + kl;
        int d = cb * 16 + n;
        float v = 0.f;
        if (k < 256) {
            int e = k >> 6, h = k & 63;
            v = w2[(e * 64 + h) * 512 + d];
        } else if (k < 260) {
            v = b2[(k - 256) * 512 + d];
        }
        w2p[op] = f2bf(v);
    } else if (idx < 131072 + 147456 + 8192) {
        // router W [K=512][N=16] (cols >=4 zero), block = kb
        int op = idx - (131072 + 147456);
        int kb = op >> 9, within = op & 511;
        int n = within >> 5, kl = within & 31;
        int k = kb * 32 + kl;
        float v = (n < 4) ? rw[k * 4 + n] : 0.f;
        rp[op] = f2bf(v);
    }
}

// ---- K1: GEMM1 + router + softmax + gelu -> H bf16 [32768][288] ----
// 64 tokens/block, 4 waves; wave w = expert w (cols 64w..64w+64).
// A-frags converted fp32->bf16 in registers (no LDS staging). One barrier (lw).
__global__ __launch_bounds__(256, 3)
void moe_g1(const float* __restrict__ x,
            const float* __restrict__ rb,
            const float* __restrict__ b1,
            const unsigned short* __restrict__ w1p,
            const unsigned short* __restrict__ rp,
            unsigned short* __restrict__ hbuf) {
    __shared__ float lw[64 * 4];

    const int tid  = threadIdx.x;
    const int lane = tid & 63, wv = tid >> 6;          // wv 0..3 = expert
    const int lr = lane & 15, lq = lane >> 4;          // A: m=lr, k=lq*8+j ; B: n=lr ; C: col=lr, row=lq*4+r
    const long t0 = (long)blockIdx.x * 64;

    v4f acc1[4][4];
    v4f accR;
    accR[0] = accR[1] = accR[2] = accR[3] = 0.f;
    #pragma unroll
    for (int mt = 0; mt < 4; ++mt)
        #pragma unroll
        for (int nt = 0; nt < 4; ++nt)
            acc1[mt][nt][0] = acc1[mt][nt][1] = acc1[mt][nt][2] = acc1[mt][nt][3] = 0.f;

    #pragma unroll 2
    for (int kb = 0; kb < 16; ++kb) {
        v8s a[4], b[4];
        #pragma unroll
        for (int mt = 0; mt < 4; ++mt) {
            const float4* p = (const float4*)(x + (size_t)(t0 + 16 * mt + lr) * 512 + kb * 32 + lq * 8);
            float4 u0 = p[0], u1 = p[1];
            uint4 c = make_uint4(pk2(u0.x, u0.y), pk2(u0.z, u0.w),
                                 pk2(u1.x, u1.y), pk2(u1.z, u1.w));
            a[mt] = __builtin_bit_cast(v8s, c);
        }
        #pragma unroll
        for (int nt = 0; nt < 4; ++nt)
            b[nt] = *(const v8s*)(const void*)&w1p[(size_t)(kb * 16 + wv * 4 + nt) * 512 + lr * 32 + lq * 8];
        v8s br = *(const v8s*)(const void*)&rp[kb * 512 + lr * 32 + lq * 8];
        // router rows 16wv.. are exactly a[wv] (block rows 64, 4 waves): free A reuse
        accR = __builtin_amdgcn_mfma_f32_16x16x32_bf16(a[wv], br, accR, 0, 0, 0);
        #pragma unroll
        for (int mt = 0; mt < 4; ++mt)
            #pragma unroll
            for (int nt = 0; nt < 4; ++nt)
                acc1[mt][nt] = __builtin_amdgcn_mfma_f32_16x16x32_bf16(a[mt], b[nt], acc1[mt][nt], 0, 0, 0);
    }

    // in-register softmax: accR[r] = logit(row = 16wv + lq*4 + r, expert = lr (lr<4))
    {
        float rbv = rb[lane & 3];
        #pragma unroll
        for (int r = 0; r < 4; ++r) {
            float v = accR[r] + rbv;
            float m = fmaxf(v, __shfl_xor(v, 1));
            m = fmaxf(m, __shfl_xor(m, 2));
            float e = __expf(v - m);
            float s = e + __shfl_xor(e, 1);
            s += __shfl_xor(s, 2);
            if (lr < 4)
                lw[(16 * wv + lq * 4 + r) * 4 + lr] = e / s;
        }
    }
    __syncthreads();   // lw visible to all waves

    // epilogue: gelu(v+b1)*wt -> hbuf[row][288]; cols 256..259 = wt, 260..287 = 0
    {
        float b1v[4];
        #pragma unroll
        for (int nt = 0; nt < 4; ++nt) b1v[nt] = b1[wv * 64 + nt * 16 + lr];
        #pragma unroll
        for (int mt = 0; mt < 4; ++mt) {
            #pragma unroll
            for (int r = 0; r < 4; ++r) {
                int row = 16 * mt + lq * 4 + r;
                float wt = lw[row * 4 + wv];
                #pragma unroll
                for (int nt = 0; nt < 4; ++nt) {
                    float v = acc1[mt][nt][r] + b1v[nt];
                    float g = gelu_fast(v) * wt;
                    hbuf[(size_t)(t0 + row) * 288 + wv * 64 + nt * 16 + lr] = f2bf(g);
                }
            }
        }
        // router-weight cols (256..259): thread tid -> row tid>>2, expert tid&3
        int rr = tid >> 2, e4 = tid & 3;
        hbuf[(size_t)(t0 + rr) * 288 + 256 + e4] = f2bf(lw[rr * 4 + e4]);
        // zero pad cols 260..287 (7 shorts per thread)
        #pragma unroll
        for (int i = 0; i < 7; ++i)
            hbuf[(size_t)(t0 + rr) * 288 + 260 + e4 * 7 + i] = 0;
    }
}

// ---- K2: GEMM2  OUT[32768][512] = H[32768][288] @ W2'. No LDS, no barriers. ----
// 1024 blocks, 4 waves each: block = (mtile = bid>>1, nhalf = bid&1);
// wave w owns cols [nhalf*256 + 64w, +64).
__global__ __launch_bounds__(256, 3)
void moe_g2(const unsigned short* __restrict__ hbuf,
            const unsigned short* __restrict__ w2p,
            float* __restrict__ out) {
    const int tid  = threadIdx.x;
    const int lane = tid & 63, wv = tid >> 6;
    const int lr = lane & 15, lq = lane >> 4;
    const long t0 = (long)(blockIdx.x >> 1) * 64;
    const int nh = blockIdx.x & 1;                 // n half: cols nh*256 ..
    const int cb0 = nh * 16 + wv * 4;              // 16-col block base for this wave

    v4f acc[4][4];
    #pragma unroll
    for (int mt = 0; mt < 4; ++mt)
        #pragma unroll
        for (int nt = 0; nt < 4; ++nt)
            acc[mt][nt][0] = acc[mt][nt][1] = acc[mt][nt][2] = acc[mt][nt][3] = 0.f;

    #pragma unroll 3
    for (int kb = 0; kb < 9; ++kb) {
        v8s a[4], b[4];
        #pragma unroll
        for (int mt = 0; mt < 4; ++mt)
            a[mt] = *(const v8s*)(const void*)&hbuf[(size_t)(t0 + 16 * mt + lr) * 288 + kb * 32 + lq * 8];
        #pragma unroll
        for (int nt = 0; nt < 4; ++nt)
            b[nt] = *(const v8s*)(const void*)&w2p[(size_t)(kb * 32 + cb0 + nt) * 512 + lr * 32 + lq * 8];
        #pragma unroll
        for (int mt = 0; mt < 4; ++mt)
            #pragma unroll
            for (int nt = 0; nt < 4; ++nt)
                acc[mt][nt] = __builtin_amdgcn_mfma_f32_16x16x32_bf16(a[mt], b[nt], acc[mt][nt], 0, 0, 0);
    }

    #pragma unroll
    for (int mt = 0; mt < 4; ++mt)
        #pragma unroll
        for (int nt = 0; nt < 4; ++nt)
            #pragma unroll
            for (int r = 0; r < 4; ++r) {
                int row = 16 * mt + lq * 4 + r;
                int col = nh * 256 + wv * 64 + 16 * nt + lr;
                out[(size_t)(t0 + row) * 512 + col] = acc[mt][nt][r];
            }
}

extern "C" void kernel_launch(void* const* d_in, const int* in_sizes, int n_in,
                              void* d_out, int out_size, void* d_ws, size_t ws_size,
                              hipStream_t stream) {
    const float* x  = (const float*)d_in[0];
    const float* rw = (const float*)d_in[1];
    const float* rb = (const float*)d_in[2];
    const float* w1 = (const float*)d_in[3];
    const float* b1 = (const float*)d_in[4];
    const float* w2 = (const float*)d_in[5];
    const float* b2 = (const float*)d_in[6];

    unsigned short* w1p  = (unsigned short*)d_ws;     // 131072 elems
    unsigned short* w2p  = w1p + 131072;              // 147456 elems
    unsigned short* rp   = w2p + 147456;              // 8192 elems
    unsigned short* hbuf = rp + 8192;                 // 32768*288 elems (~18.9 MB)

    moe_prep<<<1120, 256, 0, stream>>>(w1, w2, b2, rw, w1p, w2p, rp);
    moe_g1<<<512, 256, 0, stream>>>(x, rb, b1, w1p, rp, hbuf);
    moe_g2<<<1024, 256, 0, stream>>>(hbuf, w2p, (float*)d_out);
}